// Round 5
// baseline (2700.949 us; speedup 1.0000x reference)
//
#include <hip/hip_runtime.h>
#include <stdint.h>

// Problem constants
#define T_TOK 8192
#define DIM   2560      // D
#define DI    4096      // Di
#define NE    8         // experts
#define TOPK  2

// GEMM tiling
#define BM 128
#define BK 64
#define MAX_ROWS (T_TOK*TOPK + NE*BM)     // 17408 (padded rows upper bound)
#define MAX_TILES (T_TOK*TOPK/BM + NE)    // 136

// meta slots
#define META_NT       0
#define META_START(e) (1 + (e))
#define META_CNT(e)   (9 + (e))
#define META_ZERO     17

typedef __attribute__((ext_vector_type(4))) float f32x4;
typedef __attribute__((ext_vector_type(8))) short bf16x8;
typedef unsigned short u16;

__device__ inline u16 f2bf(float f) {
  union { float f; uint32_t u; } a; a.f = f;
  uint32_t u = a.u;
  u = (u + 0x7FFFu + ((u >> 16) & 1u)) >> 16;   // RNE
  return (u16)u;
}

__device__ inline void gload_lds16(const void* g, void* l) {
  __builtin_amdgcn_global_load_lds((const __attribute__((address_space(1))) void*)g,
                                   (__attribute__((address_space(3))) void*)l,
                                   16, 0, 0);
}

// ---------------- x fp32 -> bf16 ----------------
__global__ void cvt_x(const float* __restrict__ x, u16* __restrict__ xb) {
  int i = blockIdx.x * blockDim.x + threadIdx.x;   // one float4 per thread
  f32x4 v = ((const f32x4*)x)[i];
  typedef __attribute__((ext_vector_type(4))) u16 u16x4;
  u16x4 o = { f2bf(v[0]), f2bf(v[1]), f2bf(v[2]), f2bf(v[3]) };
  ((u16x4*)xb)[i] = o;
}

// ------- transpose+convert: in [E][R][Cn] fp32 -> out [E][Cn][R] bf16 -------
// (pass grid z=1 + pre-offset pointers for a single expert)
template<int R, int Cn>
__global__ void transpose_cvt(const float* __restrict__ in, u16* __restrict__ out) {
  __shared__ u16 tile[32][33];
  const int e = blockIdx.z;
  const int k0 = blockIdx.y * 32, n0 = blockIdx.x * 32;
  const float* src = in + (size_t)e * R * Cn;
  u16* dst = out + (size_t)e * Cn * R;
  const int tx = threadIdx.x, ty = threadIdx.y;   // 32 x 8
#pragma unroll
  for (int r = 0; r < 32; r += 8)
    tile[ty + r][tx] = f2bf(src[(size_t)(k0 + ty + r) * Cn + n0 + tx]);
  __syncthreads();
#pragma unroll
  for (int r = 0; r < 32; r += 8)
    dst[(size_t)(n0 + ty + r) * R + k0 + tx] = tile[tx][ty + r];
}

// ---------------- routing build (single block) ----------------
__global__ void build_routing(const int* __restrict__ idx, const float* __restrict__ w,
                              int* __restrict__ row_token, float* __restrict__ row_w,
                              int2* __restrict__ tdesc, int* __restrict__ meta) {
  __shared__ int scnt[NE], soff[NE + 1], sfill[NE];
  const int tid = threadIdx.x;
  if (tid < NE) { scnt[tid] = 0; sfill[tid] = 0; }
  __syncthreads();
  for (int p = tid; p < T_TOK * TOPK; p += blockDim.x)
    atomicAdd(&scnt[idx[p] & (NE - 1)], 1);
  __syncthreads();
  if (tid == 0) {
    int o = 0;
    for (int e = 0; e < NE; ++e) {
      soff[e] = o;
      o += ((scnt[e] + BM - 1) / BM) * BM;   // pad each expert segment to BM
    }
    soff[NE] = o;
    int nt = 0;
    for (int e = 0; e < NE; ++e) {
      int tiles = (scnt[e] + BM - 1) / BM;
      meta[META_START(e)] = nt;
      meta[META_CNT(e)] = tiles;
      for (int i = 0; i < tiles; ++i) { tdesc[nt] = make_int2(e, soff[e] + i * BM); ++nt; }
    }
    meta[META_NT] = nt;
    meta[META_ZERO] = 0;
  }
  __syncthreads();
  const int total = soff[NE];
  for (int r = tid; r < total; r += blockDim.x) { row_token[r] = 0; row_w[r] = 0.f; }
  __syncthreads();
  for (int p = tid; p < T_TOK * TOPK; p += blockDim.x) {
    int e = idx[p] & (NE - 1);
    int pos = atomicAdd(&sfill[e], 1);
    row_token[soff[e] + pos] = p >> 1;     // p / TOPK
    row_w[soff[e] + pos] = w[p];
  }
}

// ---------------- GEMM1: H = (gelu(x@Wg) * (x@Wu)) * w, bf16 ----------------
// Block: 128 rows x 64 H-cols. B-tile = 128 B^T rows (64 gate + 64 up).
// Bsrc/estride: B^T base and per-expert stride (0 when Bsrc is a single
// expert's buffer). Tile range: [meta[start_slot], +meta[cnt_slot]).
__global__ __launch_bounds__(256, 2) void gemm1(
    const u16* __restrict__ xb, const u16* __restrict__ Bsrc, size_t estride,
    const int* __restrict__ row_token, const float* __restrict__ row_w,
    const int2* __restrict__ tdesc, const int* __restrict__ meta,
    int start_slot, int cnt_slot,
    u16* __restrict__ H) {
  if ((int)blockIdx.y >= meta[cnt_slot]) return;
  const int2 td = tdesc[meta[start_slot] + blockIdx.y];
  const int e = td.x, row0 = td.y;
  const int n0 = blockIdx.x * 64;

  __shared__ u16 As[BM * BK];   // [128][64] bf16, 128B rows
  __shared__ u16 Bs[BM * BK];   // rows 0..63 gate n0.., rows 64..127 up n0..

  const int tid = threadIdx.x;
  const int wid = tid >> 6, lane = tid & 63;
  const int l15 = lane & 15, l4 = lane >> 4;

  const u16* Bbase = Bsrc + (size_t)e * estride;
  const u16* aptr[4]; const u16* bptr[4];
  u16* aldst[4]; u16* bldst[4];
#pragma unroll
  for (int c = 0; c < 4; ++c) {
    int off = tid * 16 + c * 4096;      // byte offset within the 16KB tile
    int r = off >> 7;                   // tile row
    int col = (off & 127) >> 1;         // element col
    int tok = row_token[row0 + r];
    aptr[c] = xb + (size_t)tok * DIM + col;
    int ng = (r < 64) ? (n0 + r) : (DI + n0 + (r - 64));
    bptr[c] = Bbase + (size_t)ng * DIM + col;
    aldst[c] = As + (c * 4096 + wid * 1024) / 2;   // wave-uniform LDS base
    bldst[c] = Bs + (c * 4096 + wid * 1024) / 2;
  }

  f32x4 accg[2][4], accu[2][4];
#pragma unroll
  for (int i = 0; i < 2; ++i)
#pragma unroll
    for (int j = 0; j < 4; ++j) { accg[i][j] = (f32x4)0.f; accu[i][j] = (f32x4)0.f; }

  for (int kt = 0; kt < DIM / BK; ++kt) {
    __syncthreads();
#pragma unroll
    for (int c = 0; c < 4; ++c) {
      gload_lds16(aptr[c], aldst[c]);
      gload_lds16(bptr[c], bldst[c]);
      aptr[c] += BK; bptr[c] += BK;
    }
    __syncthreads();
#pragma unroll
    for (int s = 0; s < 2; ++s) {
      bf16x8 af[2], bg[4], bu[4];
#pragma unroll
      for (int i = 0; i < 2; ++i) {
        int row = wid * 32 + i * 16 + l15;
        af[i] = *(const bf16x8*)((const char*)As + row * 128 + s * 64 + l4 * 16);
      }
#pragma unroll
      for (int j = 0; j < 4; ++j) {
        int rg = j * 16 + l15;
        bg[j] = *(const bf16x8*)((const char*)Bs + rg * 128 + s * 64 + l4 * 16);
        bu[j] = *(const bf16x8*)((const char*)Bs + (64 + rg) * 128 + s * 64 + l4 * 16);
      }
#pragma unroll
      for (int i = 0; i < 2; ++i)
#pragma unroll
        for (int j = 0; j < 4; ++j) {
          accg[i][j] = __builtin_amdgcn_mfma_f32_16x16x32_bf16(af[i], bg[j], accg[i][j], 0, 0, 0);
          accu[i][j] = __builtin_amdgcn_mfma_f32_16x16x32_bf16(af[i], bu[j], accu[i][j], 0, 0, 0);
        }
    }
  }

  // epilogue: h = gelu_tanh(g) * u * w  (w=0 on padded rows -> H row = 0)
#pragma unroll
  for (int i = 0; i < 2; ++i) {
#pragma unroll
    for (int el = 0; el < 4; ++el) {
      int r_local = wid * 32 + i * 16 + l4 * 4 + el;
      int grow = row0 + r_local;
      float w = row_w[grow];
      u16* hrow = H + (size_t)grow * DI + n0;
#pragma unroll
      for (int j = 0; j < 4; ++j) {
        float g = accg[i][j][el];
        float u = accu[i][j][el];
        float t = 0.7978845608028654f * (g + 0.044715f * g * g * g);
        float h = 0.5f * g * (1.f + tanhf(t)) * u * w;
        hrow[j * 16 + l15] = f2bf(h);
      }
    }
  }
}

// ---------------- GEMM2: out[tok] += H @ down^T ----------------
// Block: 128 rows x 128 out-cols; 4 waves in 2x2, each 64x64.
__global__ __launch_bounds__(256, 2) void gemm2(
    const u16* __restrict__ H, const u16* __restrict__ Bsrc, size_t estride,
    const int* __restrict__ row_token,
    const int2* __restrict__ tdesc, const int* __restrict__ meta,
    int start_slot, int cnt_slot,
    float* __restrict__ out) {
  if ((int)blockIdx.y >= meta[cnt_slot]) return;
  const int2 td = tdesc[meta[start_slot] + blockIdx.y];
  const int e = td.x, row0 = td.y;
  const int n0 = blockIdx.x * 128;

  __shared__ u16 As[BM * BK];
  __shared__ u16 Bs[BM * BK];

  const int tid = threadIdx.x;
  const int wid = tid >> 6, lane = tid & 63;
  const int wr = wid >> 1, wc = wid & 1;
  const int l15 = lane & 15, l4 = lane >> 4;

  const u16* Bbase = Bsrc + (size_t)e * estride;
  const u16* aptr[4]; const u16* bptr[4];
  u16* aldst[4]; u16* bldst[4];
#pragma unroll
  for (int c = 0; c < 4; ++c) {
    int off = tid * 16 + c * 4096;
    int r = off >> 7, col = (off & 127) >> 1;
    aptr[c] = H + (size_t)(row0 + r) * DI + col;
    bptr[c] = Bbase + (size_t)(n0 + r) * DI + col;
    aldst[c] = As + (c * 4096 + wid * 1024) / 2;
    bldst[c] = Bs + (c * 4096 + wid * 1024) / 2;
  }

  f32x4 acc[4][4];
#pragma unroll
  for (int i = 0; i < 4; ++i)
#pragma unroll
    for (int j = 0; j < 4; ++j) acc[i][j] = (f32x4)0.f;

  for (int kt = 0; kt < DI / BK; ++kt) {
    __syncthreads();
#pragma unroll
    for (int c = 0; c < 4; ++c) {
      gload_lds16(aptr[c], aldst[c]);
      gload_lds16(bptr[c], bldst[c]);
      aptr[c] += BK; bptr[c] += BK;
    }
    __syncthreads();
#pragma unroll
    for (int s = 0; s < 2; ++s) {
      bf16x8 af[4], bf_[4];
#pragma unroll
      for (int i = 0; i < 4; ++i) {
        int row = wr * 64 + i * 16 + l15;
        af[i] = *(const bf16x8*)((const char*)As + row * 128 + s * 64 + l4 * 16);
      }
#pragma unroll
      for (int j = 0; j < 4; ++j) {
        int row = wc * 64 + j * 16 + l15;
        bf_[j] = *(const bf16x8*)((const char*)Bs + row * 128 + s * 64 + l4 * 16);
      }
#pragma unroll
      for (int i = 0; i < 4; ++i)
#pragma unroll
        for (int j = 0; j < 4; ++j)
          acc[i][j] = __builtin_amdgcn_mfma_f32_16x16x32_bf16(af[i], bf_[j], acc[i][j], 0, 0, 0);
    }
  }

  // epilogue: scatter-add into out (padded rows add 0.0 to token 0 -> harmless)
#pragma unroll
  for (int i = 0; i < 4; ++i) {
#pragma unroll
    for (int el = 0; el < 4; ++el) {
      int r_local = wr * 64 + i * 16 + l4 * 4 + el;
      int tok = row_token[row0 + r_local];
      float* orow = out + (size_t)tok * DIM + n0 + wc * 64;
#pragma unroll
      for (int j = 0; j < 4; ++j)
        atomicAdd(&orow[j * 16 + l15], acc[i][j][el]);
    }
  }
}

extern "C" void kernel_launch(void* const* d_in, const int* in_sizes, int n_in,
                              void* d_out, int out_size, void* d_ws, size_t ws_size,
                              hipStream_t stream) {
  const float* x        = (const float*)d_in[0];
  const int*   topk_idx = (const int*)d_in[1];
  const float* topk_w   = (const float*)d_in[2];
  const float* gup      = (const float*)d_in[3];
  const float* down     = (const float*)d_in[4];
  float* out = (float*)d_out;

  const size_t SZ_XB   = (size_t)T_TOK * DIM * 2;         // 42 MB
  const size_t SZ_GUBT = (size_t)NE * 2 * DI * DIM * 2;   // 336 MB
  const size_t SZ_DBT  = (size_t)NE * DIM * DI * 2;       // 168 MB
  const size_t SZ_H    = (size_t)MAX_ROWS * DI * 2;       // 143 MB
  const size_t SZ_WBUF = (size_t)2 * DI * DIM * 2;        // 42 MB (one expert gu^T)
  const size_t SZ_RT   = (size_t)MAX_ROWS * 4;
  const size_t SZ_MISC = SZ_RT * 2 + MAX_TILES * 8 + 256;
  const size_t NEED_FULL = SZ_XB + SZ_GUBT + SZ_DBT + SZ_H + SZ_MISC;   // ~688 MB
  const size_t NEED_FB   = SZ_XB + SZ_WBUF + SZ_H + SZ_MISC;            // ~227 MB

  hipMemsetAsync(d_out, 0, (size_t)out_size * 4, stream);

  char* ws = (char*)d_ws;
  if (ws_size >= NEED_FULL) {
    // ---------------- fast path: all weights preconverted ----------------
    size_t o = 0;
    u16* xb    = (u16*)(ws + o); o += SZ_XB;
    u16* gub_t = (u16*)(ws + o); o += SZ_GUBT;
    u16* db_t  = (u16*)(ws + o); o += SZ_DBT;
    u16* H     = (u16*)(ws + o); o += SZ_H;
    int*   row_token = (int*)(ws + o);   o += SZ_RT;
    float* row_w     = (float*)(ws + o); o += SZ_RT;
    int2*  tdesc     = (int2*)(ws + o);  o += MAX_TILES * 8;
    int*   meta      = (int*)(ws + o);

    cvt_x<<<T_TOK * DIM / 4 / 256, 256, 0, stream>>>(x, xb);
    transpose_cvt<DIM, 2 * DI><<<dim3((2 * DI) / 32, DIM / 32, NE), dim3(32, 8), 0, stream>>>(gup, gub_t);
    transpose_cvt<DI, DIM><<<dim3(DIM / 32, DI / 32, NE), dim3(32, 8), 0, stream>>>(down, db_t);
    build_routing<<<1, 256, 0, stream>>>(topk_idx, topk_w, row_token, row_w, tdesc, meta);
    gemm1<<<dim3(DI / 64, MAX_TILES), 256, 0, stream>>>(
        xb, gub_t, (size_t)(2 * DI) * DIM, row_token, row_w, tdesc, meta, META_ZERO, META_NT, H);
    gemm2<<<dim3(DIM / 128, MAX_TILES), 256, 0, stream>>>(
        H, db_t, (size_t)DIM * DI, row_token, tdesc, meta, META_ZERO, META_NT, out);
  } else if (ws_size >= NEED_FB) {
    // -------- chunked path: one expert's weights at a time in wbuf --------
    size_t o = 0;
    u16* xb   = (u16*)(ws + o); o += SZ_XB;
    u16* wbuf = (u16*)(ws + o); o += SZ_WBUF;
    u16* H    = (u16*)(ws + o); o += SZ_H;
    int*   row_token = (int*)(ws + o);   o += SZ_RT;
    float* row_w     = (float*)(ws + o); o += SZ_RT;
    int2*  tdesc     = (int2*)(ws + o);  o += MAX_TILES * 8;
    int*   meta      = (int*)(ws + o);

    cvt_x<<<T_TOK * DIM / 4 / 256, 256, 0, stream>>>(x, xb);
    build_routing<<<1, 256, 0, stream>>>(topk_idx, topk_w, row_token, row_w, tdesc, meta);
    for (int e = 0; e < NE; ++e) {
      transpose_cvt<DIM, 2 * DI><<<dim3((2 * DI) / 32, DIM / 32, 1), dim3(32, 8), 0, stream>>>(
          gup + (size_t)e * DIM * 2 * DI, wbuf);
      gemm1<<<dim3(DI / 64, 128), 256, 0, stream>>>(
          xb, wbuf, 0, row_token, row_w, tdesc, meta, META_START(e), META_CNT(e), H);
    }
    for (int e = 0; e < NE; ++e) {
      transpose_cvt<DI, DIM><<<dim3(DIM / 32, DI / 32, 1), dim3(32, 8), 0, stream>>>(
          down + (size_t)e * DI * DIM, wbuf);
      gemm2<<<dim3(DIM / 128, 128), 256, 0, stream>>>(
          H, wbuf, 0, row_token, tdesc, meta, META_START(e), META_CNT(e), out);
    }
  }
  // else: ws too small for any path -> output stays zero (clean fail, no OOB)
}